// Round 2
// baseline (145.022 us; speedup 1.0000x reference)
//
#include <hip/hip_runtime.h>

// Problem constants: B=4, C=256, H=W=64, KS=3, N=9
#define HW    4096
#define J_TOT 16384   // B*H*W
#define K_TOT 2304    // 9*256
#define C_CH  256

typedef unsigned short u16;
typedef unsigned int   u32;
typedef __attribute__((ext_vector_type(8))) short short8;   // 8 bf16 (4 VGPRs), MFMA A/B frag
typedef __attribute__((ext_vector_type(4))) float f32x4;    // MFMA C/D frag
typedef __attribute__((ext_vector_type(8))) unsigned short us8;

__device__ __forceinline__ float b2f(u16 u) { return __uint_as_float(((u32)u) << 16); }
__device__ __forceinline__ u16 f2b(float x) {             // RNE f32->bf16
  u32 u = __float_as_uint(x);
  u += 0x7FFFu + ((u >> 16) & 1u);
  return (u16)(u >> 16);
}

// async global->LDS, 16B per lane; lds dst must be wave-uniform base (+lane*16 implicit)
__device__ __forceinline__ void gload_lds16(const u16* g, u16* l) {
  __builtin_amdgcn_global_load_lds(
      (__attribute__((address_space(1))) void*)(void*)g,
      (__attribute__((address_space(3))) void*)(void*)l, 16, 0, 0);
}

// ---------------------------------------------------------------------------
// Kernel 0: dtype detection (1 = bf16 inputs, 0 = f32 inputs).
// ---------------------------------------------------------------------------
__global__ void k_detect(const u16* __restrict__ f, int* __restrict__ flag) {
  __shared__ int sh[256];
  int t = threadIdx.x;
  int hits = 0;
  for (int i = t; i < 2048; i += 256) {
    u16 u = f[2 * i];
    int e = (u >> 7) & 0xFF;
    hits += (e >= 100 && e <= 141) ? 1 : 0;
  }
  sh[t] = hits;
  __syncthreads();
  if (t == 0) {
    int s = 0;
    for (int i = 0; i < 256; i++) s += sh[i];
    flag[0] = (s > 1024) ? 1 : 0;
  }
}

// ---------------------------------------------------------------------------
// Kernel 1: feature (b,c,h,w) -> channels-last bf16 ftr[b][hw][c]
// ---------------------------------------------------------------------------
__global__ void k_transpose(const void* __restrict__ featv, u16* __restrict__ ftr,
                            const int* __restrict__ flag) {
  __shared__ u16 tile[32][33];
  int isbf = *flag;
  int b = blockIdx.z;
  int hw0 = blockIdx.x << 5;
  int c0 = blockIdx.y << 5;
  int tx = threadIdx.x;  // 0..31 (hw on load, c on store)
  int ty = threadIdx.y;  // 0..7
  if (isbf) {
    const u16* f = (const u16*)featv;
#pragma unroll
    for (int i = 0; i < 4; i++) {
      int c = c0 + ty + i * 8;
      tile[ty + i * 8][tx] = f[(((size_t)(b * C_CH + c)) << 12) + hw0 + tx];
    }
  } else {
    const float* f = (const float*)featv;
#pragma unroll
    for (int i = 0; i < 4; i++) {
      int c = c0 + ty + i * 8;
      tile[ty + i * 8][tx] = f2b(f[(((size_t)(b * C_CH + c)) << 12) + hw0 + tx]);
    }
  }
  __syncthreads();
#pragma unroll
  for (int i = 0; i < 4; i++) {
    int hw = hw0 + ty + i * 8;
    ftr[(((size_t)(b * HW + hw)) << 8) + c0 + tx] = tile[tx][ty + i * 8];
  }
}

// ---------------------------------------------------------------------------
// Kernel 2: weight (o,c,3,3) -> Wr[o][k] bf16 with k = n*256 + c, n = i*3+j
// ---------------------------------------------------------------------------
__global__ void k_wconv(const void* __restrict__ wv, u16* __restrict__ Wr,
                        const int* __restrict__ flag) {
  int isbf = *flag;
  int idx = blockIdx.x * 256 + threadIdx.x;      // = o*2304 + n*256 + c
  if (idx >= C_CH * K_TOT) return;
  int c = idx & 255;
  int n = (idx >> 8) % 9;
  int o = idx / K_TOT;
  int src = (o * 256 + c) * 9 + n;
  if (isbf) Wr[idx] = ((const u16*)wv)[src];
  else      Wr[idx] = f2b(((const float*)wv)[src]);
}

// ---------------------------------------------------------------------------
// Kernel 3: bilinear gather -> Xt[j][k] bf16 (j = b*4096+hw, k = n*256+c).
// 16 pixels per block (1024 blocks = 4 blocks/CU). Phase 1: per (pixel,n)
// corner indices + weights. Phase 2: thread (p,cq) handles channels cq*8..+8
// and 128+cq*8..+8 -> each 16-lane group's us8 loads cover a dense 256B
// segment of a bf16 corner row.
// ---------------------------------------------------------------------------
__global__ __launch_bounds__(256) void k_gather(const void* __restrict__ offv,
                                                const u16* __restrict__ ftr,
                                                u16* __restrict__ Xt,
                                                const int* __restrict__ flag) {
  __shared__ float gs[9][4][16];
  __shared__ int   isx[9][4][16];
  int isbf = *flag;
  int j0 = blockIdx.x << 4;
  int b = j0 >> 12;
  int hw0 = j0 & (HW - 1);
  int t = threadIdx.x;

  if (t < 144) {
    int p = t & 15, n = t >> 4;
    int hw = hw0 + p;
    int h = hw >> 6, w = hw & 63;
    size_t obi = (((size_t)(b * 18 + n)) << 12) + hw;
    float ox, oy;
    if (isbf) {
      const u16* po = (const u16*)offv;
      ox = b2f(po[obi]);
      oy = b2f(po[obi + (9u << 12)]);
    } else {
      const float* po = (const float*)offv;
      ox = po[obi];
      oy = po[obi + (9u << 12)];
    }
    int ki = n / 3, kj = n % 3;
    float px = (float)(h + ki) + ox;
    float py = (float)(w + kj) + oy;
    float fx = floorf(px), fy = floorf(py);
    float qltx = fminf(fmaxf(fx, 0.f), 65.f);
    float qlty = fminf(fmaxf(fy, 0.f), 65.f);
    float qrbx = fminf(fmaxf(fx + 1.f, 0.f), 65.f);
    float qrby = fminf(fmaxf(fy + 1.f, 0.f), 65.f);
    float pcx = fminf(fmaxf(px, 0.f), 65.f);
    float pcy = fminf(fmaxf(py, 0.f), 65.f);
    float dltx = 1.f + (qltx - pcx);
    float drbx = 1.f - (qrbx - pcx);
    float dlty = 1.f + (qlty - pcy);
    float drby = 1.f - (qrby - pcy);
    float g0 = dltx * dlty;   // (q_lt_x, q_lt_y)
    float g1 = drbx * drby;   // (q_rb_x, q_rb_y)
    float g2 = dltx * drby;   // (q_lt_x, q_rb_y)
    float g3 = drbx * dlty;   // (q_rb_x, q_lt_y)
    int x0 = (int)qltx, y0 = (int)qlty, x1 = (int)qrbx, y1 = (int)qrby;
    int v0 = (x0 >= 1 && x0 <= 64 && y0 >= 1 && y0 <= 64);
    int v1 = (x1 >= 1 && x1 <= 64 && y1 >= 1 && y1 <= 64);
    int v2 = (x0 >= 1 && x0 <= 64 && y1 >= 1 && y1 <= 64);
    int v3 = (x1 >= 1 && x1 <= 64 && y0 >= 1 && y0 <= 64);
    int base = b << 12;
    isx[n][0][p] = v0 ? ((base + ((x0 - 1) << 6) + (y0 - 1)) << 8) : 0;
    isx[n][1][p] = v1 ? ((base + ((x1 - 1) << 6) + (y1 - 1)) << 8) : 0;
    isx[n][2][p] = v2 ? ((base + ((x0 - 1) << 6) + (y1 - 1)) << 8) : 0;
    isx[n][3][p] = v3 ? ((base + ((x1 - 1) << 6) + (y0 - 1)) << 8) : 0;
    gs[n][0][p] = v0 ? g0 : 0.f;
    gs[n][1][p] = v1 ? g1 : 0.f;
    gs[n][2][p] = v2 ? g2 : 0.f;
    gs[n][3][p] = v3 ? g3 : 0.f;
  }
  __syncthreads();

  int p = t >> 4, cq = t & 15;
  size_t rowb = (size_t)(j0 + p) * K_TOT;
  int cA = cq * 8, cB = 128 + cq * 8;
  for (int n = 0; n < 9; n++) {
    float g0 = gs[n][0][p], g1 = gs[n][1][p], g2 = gs[n][2][p], g3 = gs[n][3][p];
    const u16* f0 = ftr + isx[n][0][p];
    const u16* f1 = ftr + isx[n][1][p];
    const u16* f2 = ftr + isx[n][2][p];
    const u16* f3 = ftr + isx[n][3][p];
    u16* dst = Xt + rowb + n * 256;
#pragma unroll
    for (int half = 0; half < 2; half++) {
      int c = half ? cB : cA;
      us8 r0 = *(const us8*)(f0 + c);
      us8 r1 = *(const us8*)(f1 + c);
      us8 r2 = *(const us8*)(f2 + c);
      us8 r3 = *(const us8*)(f3 + c);
      us8 ov;
#pragma unroll
      for (int i = 0; i < 8; i++) {
        float v = g0 * b2f(r0[i]) + g1 * b2f(r1[i]) + g2 * b2f(r2[i]) + g3 * b2f(r3[i]);
        ov[i] = f2b(v);
      }
      *(us8*)(dst + c) = ov;
    }
  }
}

// ---------------------------------------------------------------------------
// Kernel 4: GEMM  out[o][j] = sum_k Wr[o][k]*Xt[j][k], fused epilogue
// relu(relu(acc) + feature).
//
// ob=1 restructure: block = 64j x 256o (ALL output channels), 512 threads =
// 8 waves, wave w owns o in [32w,32w+32) with the verified 64jx32o fragment
// math (2x4 frags of 16x16x32). Grid = 256 blocks = 1 block/CU. Xt (72MB,
// L3-resident) is now streamed EXACTLY ONCE (was 4x = 302MB -> the measured
// ~9.5TB/s L3 ceiling that capped rounds 0-1). Wr (1.18MB) re-staged per
// block but L2-resident per XCD. Triple-buffered BK=64 LDS (120KB), counted
// vmcnt(5): each wave stages 5x1KB per tile (1 B-gload + 4 A-gloads),
// depth-2 prefetch, one barrier per 64 K-elements. XOR-swizzle (col8 ^=
// row&7) via pre-swizzled global source, linear gload_lds dest (measured 0
// bank conflicts with this scheme).
// ---------------------------------------------------------------------------
#define NT 36   // K_TOT / 64

#define GEMM_STAGE(bufi)                                                     \
  do {                                                                       \
    gload_lds16(bsrc,  &Bs[bufi][wave * 512]);                               \
    gload_lds16(asrc0, &As[bufi][wave * 2048]);                              \
    gload_lds16(asrc1, &As[bufi][wave * 2048 + 512]);                        \
    gload_lds16(asrc2, &As[bufi][wave * 2048 + 1024]);                       \
    gload_lds16(asrc3, &As[bufi][wave * 2048 + 1536]);                       \
    bsrc += 64; asrc0 += 64; asrc1 += 64; asrc2 += 64; asrc3 += 64;          \
  } while (0)

#define GEMM_COMPUTE(bufi)                                                   \
  do {                                                                       \
    short8 af[2][2], bf[4][2];                                               \
    _Pragma("unroll")                                                        \
    for (int kk = 0; kk < 2; kk++) {                                         \
      int go = (((kk << 2) + lk) ^ swz) << 3;                                \
      _Pragma("unroll")                                                      \
      for (int oi = 0; oi < 2; oi++)                                         \
        af[oi][kk] = *(const short8*)(As[bufi] + (wave * 32 + oi * 16 + lr) * 64 + go); \
      _Pragma("unroll")                                                      \
      for (int ji = 0; ji < 4; ji++)                                         \
        bf[ji][kk] = *(const short8*)(Bs[bufi] + (ji * 16 + lr) * 64 + go);  \
    }                                                                        \
    __builtin_amdgcn_s_setprio(1);                                           \
    _Pragma("unroll")                                                        \
    for (int kk = 0; kk < 2; kk++)                                           \
      _Pragma("unroll")                                                      \
      for (int oi = 0; oi < 2; oi++)                                         \
        _Pragma("unroll")                                                    \
        for (int ji = 0; ji < 4; ji++)                                       \
          acc[oi][ji] = __builtin_amdgcn_mfma_f32_16x16x32_bf16(             \
              af[oi][kk], bf[ji][kk], acc[oi][ji], 0, 0, 0);                 \
    __builtin_amdgcn_s_setprio(0);                                           \
  } while (0)

__global__ __launch_bounds__(512) void k_gemm(const u16* __restrict__ Wr,
                                              const u16* __restrict__ Xt,
                                              const void* __restrict__ featv,
                                              void* __restrict__ outv,
                                              const int* __restrict__ flag) {
  __shared__ u16 Bs[3][64 * 64];    // [j_row][k]  8KB x3
  __shared__ u16 As[3][256 * 64];   // [o_row][k] 32KB x3  (total 120KB)
  int isbf = *flag;
  asm volatile("" :: "s"(isbf));
  int jb = blockIdx.x << 6;
  int t = threadIdx.x;
  int wave = t >> 6, lane = t & 63;
  int lr = lane & 15, lk = lane >> 4;
  int swz = lr & 7;

  f32x4 acc[2][4];   // [oi][ji]
  f32x4 zero = {0.f, 0.f, 0.f, 0.f};
#pragma unroll
  for (int i = 0; i < 2; i++)
#pragma unroll
    for (int j = 0; j < 4; j++) acc[i][j] = zero;

  // staging: wave w stages B rows [8w,8w+8) (1 instr) and A rows [32w,32w+32)
  // (4 instrs). Lane l covers row +(l>>3), col-group l&7; source column
  // pre-swizzled cg_src = (l&7)^(l>>3) so LDS slot (r,cg) holds global
  // column (cg ^ (r&7)); row offsets are multiples of 8 so row&7 == l>>3.
  int rb = lane >> 3;                  // 0..7
  int cs = ((lane & 7) ^ rb) << 3;     // pre-swizzled source k-offset (elems)
  const u16* bsrc  = Xt + (size_t)(jb + wave * 8 + rb) * K_TOT + cs;
  const u16* asrc0 = Wr + (size_t)(wave * 32 +  0 + rb) * K_TOT + cs;
  const u16* asrc1 = Wr + (size_t)(wave * 32 +  8 + rb) * K_TOT + cs;
  const u16* asrc2 = Wr + (size_t)(wave * 32 + 16 + rb) * K_TOT + cs;
  const u16* asrc3 = Wr + (size_t)(wave * 32 + 24 + rb) * K_TOT + cs;

  // prologue: fill buffers 0 and 1; wait for buffer 0 only (10 -> 5 in flight)
  GEMM_STAGE(0);
  GEMM_STAGE(1);
  asm volatile("s_waitcnt vmcnt(5)" ::: "memory");
  __builtin_amdgcn_s_barrier();

  int cb = 0, sb = 2;
  for (int tt = 0; tt < NT - 2; ++tt) {
    GEMM_STAGE(sb);          // tile tt+2 in flight
    GEMM_COMPUTE(cb);        // tile tt
    // wait for tile tt+1's stage (issued last iter); tt+2's 5 stay in flight
    asm volatile("s_waitcnt vmcnt(5)" ::: "memory");
    __builtin_amdgcn_s_barrier();
    cb = (cb + 1 == 3) ? 0 : cb + 1;
    sb = (sb + 1 == 3) ? 0 : sb + 1;
  }
  GEMM_COMPUTE(cb);          // tile NT-2
  asm volatile("s_waitcnt vmcnt(0)" ::: "memory");
  __builtin_amdgcn_s_barrier();
  cb = (cb + 1 == 3) ? 0 : cb + 1;
  GEMM_COMPUTE(cb);          // tile NT-1

  // epilogue: D mapping col = lane&15 (j), row = (lane>>4)*4 + r (o)
  int lq = lane >> 4;
#pragma unroll
  for (int oi = 0; oi < 2; oi++) {
#pragma unroll
    for (int ji = 0; ji < 4; ji++) {
      int j = jb + ji * 16 + lr;
      int bb_ = j >> 12, hw = j & (HW - 1);
      int o0 = wave * 32 + oi * 16 + lq * 4;
#pragma unroll
      for (int r = 0; r < 4; r++) {
        size_t oidx = (((size_t)(bb_ * C_CH + o0 + r)) << 12) + hw;
        float v = acc[oi][ji][r];
        v = fmaxf(v, 0.f);
        float ft = isbf ? b2f(((const u16*)featv)[oidx]) : ((const float*)featv)[oidx];
        v = fmaxf(v + ft, 0.f);
        if (isbf) ((u16*)outv)[oidx] = f2b(v);
        else      ((float*)outv)[oidx] = v;
      }
    }
  }
}

extern "C" void kernel_launch(void* const* d_in, const int* in_sizes, int n_in,
                              void* d_out, int out_size, void* d_ws, size_t ws_size,
                              hipStream_t stream) {
  const void* feat = d_in[0];
  const void* offs = d_in[1];
  const void* wght = d_in[2];

  // workspace layout (256B-aligned sections), total ~85.1 MB
  const size_t off_flag = 0;
  const size_t off_wr   = 256;                          // bf16 Wr, 1.125 MB
  const size_t off_ftr  = off_wr + (size_t)1179648;     // bf16 channels-last feature, 8 MB
  const size_t off_xt   = off_ftr + (size_t)8388608;    // bf16 Xt, 72 MB
  const size_t need     = off_xt + (size_t)75497472;
  if (ws_size < need) return;  // insufficient scratch; cannot run

  char* ws = (char*)d_ws;
  int* flag = (int*)(ws + off_flag);
  u16* Wr   = (u16*)(ws + off_wr);
  u16* ftr  = (u16*)(ws + off_ftr);
  u16* Xt   = (u16*)(ws + off_xt);

  k_detect<<<1, 256, 0, stream>>>((const u16*)feat, flag);
  k_transpose<<<dim3(128, 8, 4), dim3(32, 8), 0, stream>>>(feat, ftr, flag);
  k_wconv<<<K_TOT, 256, 0, stream>>>(wght, Wr, flag);
  k_gather<<<J_TOT / 16, 256, 0, stream>>>(offs, ftr, Xt, flag);
  k_gemm<<<J_TOT / 64, 512, 0, stream>>>(Wr, Xt, feat, d_out, flag);
}

// Round 3
// 140.793 us; speedup vs baseline: 1.0300x; 1.0300x over previous
//
#include <hip/hip_runtime.h>

// Problem constants: B=4, C=256, H=W=64, KS=3, N=9
#define HW    4096
#define J_TOT 16384   // B*H*W
#define K_TOT 2304    // 9*256
#define C_CH  256

typedef unsigned short u16;
typedef unsigned int   u32;
typedef __attribute__((ext_vector_type(8))) short short8;   // 8 bf16 (4 VGPRs), MFMA A/B frag
typedef __attribute__((ext_vector_type(4))) float f32x4;    // MFMA C/D frag
typedef __attribute__((ext_vector_type(8))) unsigned short us8;

__device__ __forceinline__ float b2f(u16 u) { return __uint_as_float(((u32)u) << 16); }
__device__ __forceinline__ u16 f2b(float x) {             // RNE f32->bf16
  u32 u = __float_as_uint(x);
  u += 0x7FFFu + ((u >> 16) & 1u);
  return (u16)(u >> 16);
}

// async global->LDS, 16B per lane; lds dst must be wave-uniform base (+lane*16 implicit)
__device__ __forceinline__ void gload_lds16(const u16* g, u16* l) {
  __builtin_amdgcn_global_load_lds(
      (__attribute__((address_space(1))) void*)(void*)g,
      (__attribute__((address_space(3))) void*)(void*)l, 16, 0, 0);
}

// ---------------------------------------------------------------------------
// Kernel 0: dtype detection (1 = bf16 inputs, 0 = f32 inputs).
// ---------------------------------------------------------------------------
__global__ void k_detect(const u16* __restrict__ f, int* __restrict__ flag) {
  __shared__ int sh[256];
  int t = threadIdx.x;
  int hits = 0;
  for (int i = t; i < 2048; i += 256) {
    u16 u = f[2 * i];
    int e = (u >> 7) & 0xFF;
    hits += (e >= 100 && e <= 141) ? 1 : 0;
  }
  sh[t] = hits;
  __syncthreads();
  if (t == 0) {
    int s = 0;
    for (int i = 0; i < 256; i++) s += sh[i];
    flag[0] = (s > 1024) ? 1 : 0;
  }
}

// ---------------------------------------------------------------------------
// Kernel 1: feature (b,c,h,w) -> channels-last bf16 ftr[b][hw][c]
// ---------------------------------------------------------------------------
__global__ void k_transpose(const void* __restrict__ featv, u16* __restrict__ ftr,
                            const int* __restrict__ flag) {
  __shared__ u16 tile[32][33];
  int isbf = *flag;
  int b = blockIdx.z;
  int hw0 = blockIdx.x << 5;
  int c0 = blockIdx.y << 5;
  int tx = threadIdx.x;  // 0..31 (hw on load, c on store)
  int ty = threadIdx.y;  // 0..7
  if (isbf) {
    const u16* f = (const u16*)featv;
#pragma unroll
    for (int i = 0; i < 4; i++) {
      int c = c0 + ty + i * 8;
      tile[ty + i * 8][tx] = f[(((size_t)(b * C_CH + c)) << 12) + hw0 + tx];
    }
  } else {
    const float* f = (const float*)featv;
#pragma unroll
    for (int i = 0; i < 4; i++) {
      int c = c0 + ty + i * 8;
      tile[ty + i * 8][tx] = f2b(f[(((size_t)(b * C_CH + c)) << 12) + hw0 + tx]);
    }
  }
  __syncthreads();
#pragma unroll
  for (int i = 0; i < 4; i++) {
    int hw = hw0 + ty + i * 8;
    ftr[(((size_t)(b * HW + hw)) << 8) + c0 + tx] = tile[tx][ty + i * 8];
  }
}

// ---------------------------------------------------------------------------
// Kernel 2: weight (o,c,3,3) -> Wr[o][k] bf16 with k = n*256 + c, n = i*3+j
// ---------------------------------------------------------------------------
__global__ void k_wconv(const void* __restrict__ wv, u16* __restrict__ Wr,
                        const int* __restrict__ flag) {
  int isbf = *flag;
  int idx = blockIdx.x * 256 + threadIdx.x;      // = o*2304 + n*256 + c
  if (idx >= C_CH * K_TOT) return;
  int c = idx & 255;
  int n = (idx >> 8) % 9;
  int o = idx / K_TOT;
  int src = (o * 256 + c) * 9 + n;
  if (isbf) Wr[idx] = ((const u16*)wv)[src];
  else      Wr[idx] = f2b(((const float*)wv)[src]);
}

// ---------------------------------------------------------------------------
// Kernel 3 (FUSED gather+GEMM): out[o][j] = sum_k Wr[o][k]*B[j][k] with
// B[j][n*256+c] = bilinear-gathered feature, produced ON THE FLY in LDS.
// Eliminates the 72MB Xt HBM round-trip and the standalone k_gather kernel.
//
// Block = 64j x 256o, 512 threads = 8 waves, wave w owns o[32w,32w+32)
// (2x4 frags of 16x16x32, verified mapping). Grid 256 = 1 block/CU.
//
// Phase 0: per-block corner indices/weights for 64 pixels x 9 n (verified
// k_gather math, unchanged). K-loop (36 tiles of BK=64, double-buffered):
//   PLOAD(t+1): issue 4 corner us8 loads per thread (T14 issue-early)
//   A_DMA(t+1): 4 gload_lds16 per wave (Wr rows, pre-swizzled source)
//   COMPUTE(t): 12 ds_read_b128 + 16 MFMA per wave (hides corner-load lat)
//   PFIN(t+1):  bilinear FMA + f2b + one ds_write_b128 per thread
//   __syncthreads()
// B swizzle: producer thread (p,cg) writes slot (p, cg^(p&7)); reader takes
// group g from slot g^(row&7) -- bank-uniform both sides (0 conflicts
// measured for this scheme in rounds 1-2). A staging identical to round 2.
// LDS: As 2x32KB + Bs 2x8KB + gs/isx 18KB = 98KB.
// ---------------------------------------------------------------------------
#define NT 36   // K_TOT / 64

#define A_DMA(bufi)                                                          \
  do {                                                                       \
    gload_lds16(asrc0, &As[bufi][wave * 2048]);                              \
    gload_lds16(asrc1, &As[bufi][wave * 2048 + 512]);                        \
    gload_lds16(asrc2, &As[bufi][wave * 2048 + 1024]);                       \
    gload_lds16(asrc3, &As[bufi][wave * 2048 + 1536]);                       \
    asrc0 += 64; asrc1 += 64; asrc2 += 64; asrc3 += 64;                      \
  } while (0)

#define PLOAD(tile)                                                          \
  do {                                                                       \
    int np = (tile) >> 2, c0 = ((tile) & 3) << 6;                            \
    w0 = gs[np][0][pp]; w1 = gs[np][1][pp];                                  \
    w2 = gs[np][2][pp]; w3 = gs[np][3][pp];                                  \
    q0 = *(const us8*)(ftr + isx[np][0][pp] + c0 + cb8);                     \
    q1 = *(const us8*)(ftr + isx[np][1][pp] + c0 + cb8);                     \
    q2 = *(const us8*)(ftr + isx[np][2][pp] + c0 + cb8);                     \
    q3 = *(const us8*)(ftr + isx[np][3][pp] + c0 + cb8);                     \
  } while (0)

#define PFIN(bufi)                                                           \
  do {                                                                       \
    us8 ov;                                                                  \
    _Pragma("unroll")                                                        \
    for (int i = 0; i < 8; i++) {                                            \
      float v = w0 * b2f(q0[i]) + w1 * b2f(q1[i]) +                          \
                w2 * b2f(q2[i]) + w3 * b2f(q3[i]);                           \
      ov[i] = f2b(v);                                                        \
    }                                                                        \
    *(us8*)(&Bs[bufi][bofs]) = ov;                                           \
  } while (0)

#define GEMM_COMPUTE(bufi)                                                   \
  do {                                                                       \
    short8 af[2][2], bf[4][2];                                               \
    _Pragma("unroll")                                                        \
    for (int kk = 0; kk < 2; kk++) {                                         \
      int go = (((kk << 2) + lk) ^ swz) << 3;                                \
      _Pragma("unroll")                                                      \
      for (int oi = 0; oi < 2; oi++)                                         \
        af[oi][kk] = *(const short8*)(As[bufi] + (wave * 32 + oi * 16 + lr) * 64 + go); \
      _Pragma("unroll")                                                      \
      for (int ji = 0; ji < 4; ji++)                                         \
        bf[ji][kk] = *(const short8*)(Bs[bufi] + (ji * 16 + lr) * 64 + go);  \
    }                                                                        \
    __builtin_amdgcn_s_setprio(1);                                           \
    _Pragma("unroll")                                                        \
    for (int kk = 0; kk < 2; kk++)                                           \
      _Pragma("unroll")                                                      \
      for (int oi = 0; oi < 2; oi++)                                         \
        _Pragma("unroll")                                                    \
        for (int ji = 0; ji < 4; ji++)                                       \
          acc[oi][ji] = __builtin_amdgcn_mfma_f32_16x16x32_bf16(             \
              af[oi][kk], bf[ji][kk], acc[oi][ji], 0, 0, 0);                 \
    __builtin_amdgcn_s_setprio(0);                                           \
  } while (0)

__global__ __launch_bounds__(512) void k_gemm(const u16* __restrict__ Wr,
                                              const u16* __restrict__ ftr,
                                              const void* __restrict__ offv,
                                              const void* __restrict__ featv,
                                              void* __restrict__ outv,
                                              const int* __restrict__ flag) {
  __shared__ u16 As[2][256 * 64];   // [o_row][k] 32KB x2
  __shared__ u16 Bs[2][64 * 64];    // [j_row][k]  8KB x2
  __shared__ float gs[9][4][64];    // bilinear weights, 9KB
  __shared__ int   isx[9][4][64];   // corner base offsets (elem, row<<8), 9KB
  int isbf = *flag;
  int j0 = blockIdx.x << 6;
  int b = j0 >> 12;
  int hw0 = j0 & (HW - 1);
  int t = threadIdx.x;
  int wave = t >> 6, lane = t & 63;
  int lr = lane & 15, lk = lane >> 4;
  int swz = lr & 7;

  // ---- phase 0: corner indices + weights for 64 pixels x 9 n (verified) ----
  for (int e = t; e < 576; e += 512) {
    int n = e >> 6, p = e & 63;
    int hw = hw0 + p;
    int h = hw >> 6, w = hw & 63;
    size_t obi = (((size_t)(b * 18 + n)) << 12) + hw;
    float ox, oy;
    if (isbf) {
      const u16* po = (const u16*)offv;
      ox = b2f(po[obi]);
      oy = b2f(po[obi + (9u << 12)]);
    } else {
      const float* po = (const float*)offv;
      ox = po[obi];
      oy = po[obi + (9u << 12)];
    }
    int ki = n / 3, kj = n % 3;
    float px = (float)(h + ki) + ox;
    float py = (float)(w + kj) + oy;
    float fx = floorf(px), fy = floorf(py);
    float qltx = fminf(fmaxf(fx, 0.f), 65.f);
    float qlty = fminf(fmaxf(fy, 0.f), 65.f);
    float qrbx = fminf(fmaxf(fx + 1.f, 0.f), 65.f);
    float qrby = fminf(fmaxf(fy + 1.f, 0.f), 65.f);
    float pcx = fminf(fmaxf(px, 0.f), 65.f);
    float pcy = fminf(fmaxf(py, 0.f), 65.f);
    float dltx = 1.f + (qltx - pcx);
    float drbx = 1.f - (qrbx - pcx);
    float dlty = 1.f + (qlty - pcy);
    float drby = 1.f - (qrby - pcy);
    float g0 = dltx * dlty;   // (q_lt_x, q_lt_y)
    float g1 = drbx * drby;   // (q_rb_x, q_rb_y)
    float g2 = dltx * drby;   // (q_lt_x, q_rb_y)
    float g3 = drbx * dlty;   // (q_rb_x, q_lt_y)
    int x0 = (int)qltx, y0 = (int)qlty, x1 = (int)qrbx, y1 = (int)qrby;
    int v0 = (x0 >= 1 && x0 <= 64 && y0 >= 1 && y0 <= 64);
    int v1 = (x1 >= 1 && x1 <= 64 && y1 >= 1 && y1 <= 64);
    int v2 = (x0 >= 1 && x0 <= 64 && y1 >= 1 && y1 <= 64);
    int v3 = (x1 >= 1 && x1 <= 64 && y0 >= 1 && y0 <= 64);
    int base = b << 12;
    isx[n][0][p] = v0 ? ((base + ((x0 - 1) << 6) + (y0 - 1)) << 8) : 0;
    isx[n][1][p] = v1 ? ((base + ((x1 - 1) << 6) + (y1 - 1)) << 8) : 0;
    isx[n][2][p] = v2 ? ((base + ((x0 - 1) << 6) + (y1 - 1)) << 8) : 0;
    isx[n][3][p] = v3 ? ((base + ((x1 - 1) << 6) + (y0 - 1)) << 8) : 0;
    gs[n][0][p] = v0 ? g0 : 0.f;
    gs[n][1][p] = v1 ? g1 : 0.f;
    gs[n][2][p] = v2 ? g2 : 0.f;
    gs[n][3][p] = v3 ? g3 : 0.f;
  }

  f32x4 acc[2][4];   // [oi][ji]
  f32x4 zero = {0.f, 0.f, 0.f, 0.f};
#pragma unroll
  for (int i = 0; i < 2; i++)
#pragma unroll
    for (int j = 0; j < 4; j++) acc[i][j] = zero;

  // A staging (identical to round 2): wave w stages A rows [32w,32w+32) via
  // 4 instrs; lane l covers row +(l>>3), source col-group pre-swizzled
  // (l&7)^(l>>3) so LDS slot (r,cg) holds global column (cg ^ (r&7)).
  int rb = lane >> 3;
  int cs = ((lane & 7) ^ rb) << 3;
  const u16* asrc0 = Wr + (size_t)(wave * 32 +  0 + rb) * K_TOT + cs;
  const u16* asrc1 = Wr + (size_t)(wave * 32 +  8 + rb) * K_TOT + cs;
  const u16* asrc2 = Wr + (size_t)(wave * 32 + 16 + rb) * K_TOT + cs;
  const u16* asrc3 = Wr + (size_t)(wave * 32 + 24 + rb) * K_TOT + cs;

  // B producer: thread (p = t>>3, cg = t&7) owns one us8 of the 64x64 tile.
  int pp = t >> 3, cg = t & 7;
  int bofs = pp * 64 + ((cg ^ (pp & 7)) << 3);   // swizzled LDS elem offset
  int cb8 = cg << 3;                              // channel offset in 64-chunk

  __syncthreads();   // phase-0 tables ready

  us8 q0, q1, q2, q3;
  float w0, w1, w2, w3;

  // prologue: produce tile 0 + stage A tile 0 into buffer 0
  PLOAD(0);
  A_DMA(0);
  PFIN(0);
  __syncthreads();

  for (int tt = 0; tt < NT - 1; ++tt) {
    int cbuf = tt & 1, nbuf = cbuf ^ 1;
    PLOAD(tt + 1);          // corner loads in flight
    A_DMA(nbuf);            // Wr DMA in flight
    GEMM_COMPUTE(cbuf);     // MFMA on current tile hides the latency
    PFIN(nbuf);             // interp + ds_write next B tile
    __syncthreads();        // drains vmcnt+lgkmcnt; all buffers coherent
  }
  GEMM_COMPUTE((NT - 1) & 1);

  // epilogue: D mapping col = lane&15 (j), row = (lane>>4)*4 + r (o)
  int lq = lane >> 4;
#pragma unroll
  for (int oi = 0; oi < 2; oi++) {
#pragma unroll
    for (int ji = 0; ji < 4; ji++) {
      int j = j0 + ji * 16 + lr;
      int bb_ = j >> 12, hw = j & (HW - 1);
      int o0 = wave * 32 + oi * 16 + lq * 4;
#pragma unroll
      for (int r = 0; r < 4; r++) {
        size_t oidx = (((size_t)(bb_ * C_CH + o0 + r)) << 12) + hw;
        float v = acc[oi][ji][r];
        v = fmaxf(v, 0.f);
        float ft = isbf ? b2f(((const u16*)featv)[oidx]) : ((const float*)featv)[oidx];
        v = fmaxf(v + ft, 0.f);
        if (isbf) ((u16*)outv)[oidx] = f2b(v);
        else      ((float*)outv)[oidx] = v;
      }
    }
  }
}

extern "C" void kernel_launch(void* const* d_in, const int* in_sizes, int n_in,
                              void* d_out, int out_size, void* d_ws, size_t ws_size,
                              hipStream_t stream) {
  const void* feat = d_in[0];
  const void* offs = d_in[1];
  const void* wght = d_in[2];

  // workspace layout (256B-aligned sections); Xt no longer materialized
  const size_t off_flag = 0;
  const size_t off_wr   = 256;                          // bf16 Wr, 1.125 MB
  const size_t off_ftr  = off_wr + (size_t)1179648;     // bf16 channels-last feature, 8 MB
  const size_t need     = off_ftr + (size_t)8388608;
  if (ws_size < need) return;  // insufficient scratch; cannot run

  char* ws = (char*)d_ws;
  int* flag = (int*)(ws + off_flag);
  u16* Wr   = (u16*)(ws + off_wr);
  u16* ftr  = (u16*)(ws + off_ftr);

  k_detect<<<1, 256, 0, stream>>>((const u16*)feat, flag);
  k_transpose<<<dim3(128, 8, 4), dim3(32, 8), 0, stream>>>(feat, ftr, flag);
  k_wconv<<<K_TOT, 256, 0, stream>>>(wght, Wr, flag);
  k_gemm<<<J_TOT / 64, 512, 0, stream>>>(Wr, ftr, offs, feat, d_out, flag);
}

// Round 4
// 136.413 us; speedup vs baseline: 1.0631x; 1.0321x over previous
//
#include <hip/hip_runtime.h>

// Problem constants: B=4, C=256, H=W=64, KS=3, N=9
#define HW    4096
#define J_TOT 16384   // B*H*W
#define K_TOT 2304    // 9*256
#define C_CH  256

typedef unsigned short u16;
typedef unsigned int   u32;
typedef __attribute__((ext_vector_type(8))) short short8;   // 8 bf16 (4 VGPRs), MFMA A/B frag
typedef __attribute__((ext_vector_type(4))) float f32x4;    // MFMA C/D frag
typedef __attribute__((ext_vector_type(8))) unsigned short us8;

__device__ __forceinline__ float b2f(u16 u) { return __uint_as_float(((u32)u) << 16); }
__device__ __forceinline__ u16 f2b(float x) {             // RNE f32->bf16
  u32 u = __float_as_uint(x);
  u += 0x7FFFu + ((u >> 16) & 1u);
  return (u16)(u >> 16);
}

// async global->LDS, 16B per lane; lds dst must be wave-uniform base (+lane*16 implicit)
__device__ __forceinline__ void gload_lds16(const u16* g, u16* l) {
  __builtin_amdgcn_global_load_lds(
      (__attribute__((address_space(1))) void*)(void*)g,
      (__attribute__((address_space(3))) void*)(void*)l, 16, 0, 0);
}

// ---------------------------------------------------------------------------
// Kernel 0: dtype detection (1 = bf16 inputs, 0 = f32 inputs).
// ---------------------------------------------------------------------------
__global__ void k_detect(const u16* __restrict__ f, int* __restrict__ flag) {
  __shared__ int sh[256];
  int t = threadIdx.x;
  int hits = 0;
  for (int i = t; i < 2048; i += 256) {
    u16 u = f[2 * i];
    int e = (u >> 7) & 0xFF;
    hits += (e >= 100 && e <= 141) ? 1 : 0;
  }
  sh[t] = hits;
  __syncthreads();
  if (t == 0) {
    int s = 0;
    for (int i = 0; i < 256; i++) s += sh[i];
    flag[0] = (s > 1024) ? 1 : 0;
  }
}

// ---------------------------------------------------------------------------
// Kernel 1 (merged prep): z<4 -> feature (b,c,h,w) -> channels-last bf16
// ftr[b][hw][c] (b = blockIdx.z); z==4 -> weight (o,c,3,3) -> Wr[o][k],
// k = n*256+c. One launch instead of two.
// ---------------------------------------------------------------------------
__global__ void k_prep(const void* __restrict__ featv, u16* __restrict__ ftr,
                       const void* __restrict__ wv, u16* __restrict__ Wr,
                       const int* __restrict__ flag) {
  int isbf = *flag;
  int tx = threadIdx.x;  // 0..31
  int ty = threadIdx.y;  // 0..7
  int z = blockIdx.z;
  if (z < 4) {
    __shared__ u16 tile[32][33];
    int b = z;
    int hw0 = blockIdx.x << 5;
    int c0 = blockIdx.y << 5;
    if (isbf) {
      const u16* f = (const u16*)featv;
#pragma unroll
      for (int i = 0; i < 4; i++) {
        int c = c0 + ty + i * 8;
        tile[ty + i * 8][tx] = f[(((size_t)(b * C_CH + c)) << 12) + hw0 + tx];
      }
    } else {
      const float* f = (const float*)featv;
#pragma unroll
      for (int i = 0; i < 4; i++) {
        int c = c0 + ty + i * 8;
        tile[ty + i * 8][tx] = f2b(f[(((size_t)(b * C_CH + c)) << 12) + hw0 + tx]);
      }
    }
    __syncthreads();
#pragma unroll
    for (int i = 0; i < 4; i++) {
      int hw = hw0 + ty + i * 8;
      ftr[(((size_t)(b * HW + hw)) << 8) + c0 + tx] = tile[tx][ty + i * 8];
    }
  } else {
    // weight repack: 1024 blocks x 256 threads, grid-stride over 589824 elems
    int bid = blockIdx.x + (blockIdx.y << 7);
    int flat = ty * 32 + tx;
    for (int idx = bid * 256 + flat; idx < C_CH * K_TOT; idx += 1024 * 256) {
      int c = idx & 255;
      int n = (idx >> 8) % 9;
      int o = idx / K_TOT;
      int src = (o * 256 + c) * 9 + n;
      if (isbf) Wr[idx] = ((const u16*)wv)[src];
      else      Wr[idx] = f2b(((const float*)wv)[src]);
    }
  }
}

// ---------------------------------------------------------------------------
// Kernel 2 (FUSED gather+GEMM): out[o][j] = sum_k Wr[o][k]*B[j][k] with
// B[j][n*256+c] = bilinear-gathered feature, produced ON THE FLY in LDS.
//
// Occupancy restructure vs round 3: block = 64j x 128o (o split across
// blockIdx.y), 512 threads = 8 waves as 2j x 4o, wave tile 32j x 32o
// (2x2 frags of 16x16x32). Grid (256,2) = 512 blocks = 2 blocks/CU =
// 4 waves/SIMD -- a second INDEPENDENT block per CU fills the per-iteration
// barrier/latency stalls that capped round 3 (Occ 21%, MfmaUtil 10%,
// VALU 22% => ~68% dead cycles at 1 block/CU lockstep).
// Cost: gather work duplicated x2 (cheap: VALU was 22% busy).
//
// LDS 66KB: As 2x16KB + Bs 2x8KB + tables 18KB. B producer mapping is
// byte-identical to round 3 (thread (p,cg) -> one us8, swizzled slot
// (p, cg^(p&7)); reader group g from slot g^(row&7); 0 conflicts measured).
// A staging: wave w stages rows [16w,16w+16) via 2 gload_lds16, source
// column pre-swizzled (l&7)^(l>>3).
// ---------------------------------------------------------------------------
#define NT 36   // K_TOT / 64

#define A_DMA(bufi)                                                          \
  do {                                                                       \
    gload_lds16(asrc0, &As[bufi][wave * 1024]);                              \
    gload_lds16(asrc1, &As[bufi][wave * 1024 + 512]);                        \
    asrc0 += 64; asrc1 += 64;                                                \
  } while (0)

#define PLOAD(tile)                                                          \
  do {                                                                       \
    int np = (tile) >> 2, c0 = ((tile) & 3) << 6;                            \
    w0 = gs[np][0][pp]; w1 = gs[np][1][pp];                                  \
    w2 = gs[np][2][pp]; w3 = gs[np][3][pp];                                  \
    q0 = *(const us8*)(ftr + isx[np][0][pp] + c0 + cb8);                     \
    q1 = *(const us8*)(ftr + isx[np][1][pp] + c0 + cb8);                     \
    q2 = *(const us8*)(ftr + isx[np][2][pp] + c0 + cb8);                     \
    q3 = *(const us8*)(ftr + isx[np][3][pp] + c0 + cb8);                     \
  } while (0)

#define PFIN(bufi)                                                           \
  do {                                                                       \
    us8 ov;                                                                  \
    _Pragma("unroll")                                                        \
    for (int i = 0; i < 8; i++) {                                            \
      float v = w0 * b2f(q0[i]) + w1 * b2f(q1[i]) +                          \
                w2 * b2f(q2[i]) + w3 * b2f(q3[i]);                           \
      ov[i] = f2b(v);                                                        \
    }                                                                        \
    *(us8*)(&Bs[bufi][bofs]) = ov;                                           \
  } while (0)

#define GEMM_COMPUTE(bufi)                                                   \
  do {                                                                       \
    short8 af[2][2], bf[2][2];                                               \
    _Pragma("unroll")                                                        \
    for (int kk = 0; kk < 2; kk++) {                                         \
      int go = (((kk << 2) + lk) ^ swz) << 3;                                \
      _Pragma("unroll")                                                      \
      for (int oi = 0; oi < 2; oi++)                                         \
        af[oi][kk] = *(const short8*)(As[bufi] + (wo * 32 + oi * 16 + lr) * 64 + go); \
      _Pragma("unroll")                                                      \
      for (int ji = 0; ji < 2; ji++)                                         \
        bf[ji][kk] = *(const short8*)(Bs[bufi] + (wj * 32 + ji * 16 + lr) * 64 + go); \
    }                                                                        \
    __builtin_amdgcn_s_setprio(1);                                           \
    _Pragma("unroll")                                                        \
    for (int kk = 0; kk < 2; kk++)                                           \
      _Pragma("unroll")                                                      \
      for (int oi = 0; oi < 2; oi++)                                         \
        _Pragma("unroll")                                                    \
        for (int ji = 0; ji < 2; ji++)                                       \
          acc[oi][ji] = __builtin_amdgcn_mfma_f32_16x16x32_bf16(             \
              af[oi][kk], bf[ji][kk], acc[oi][ji], 0, 0, 0);                 \
    __builtin_amdgcn_s_setprio(0);                                           \
  } while (0)

__global__ __launch_bounds__(512) void k_gemm(const u16* __restrict__ Wr,
                                              const u16* __restrict__ ftr,
                                              const void* __restrict__ offv,
                                              const void* __restrict__ featv,
                                              void* __restrict__ outv,
                                              const int* __restrict__ flag) {
  __shared__ u16 As[2][128 * 64];   // [o_row][k] 16KB x2
  __shared__ u16 Bs[2][64 * 64];    // [j_row][k]  8KB x2
  __shared__ float gs[9][4][64];    // bilinear weights, 9KB
  __shared__ int   isx[9][4][64];   // corner base offsets (elem, row<<8), 9KB
  int isbf = *flag;
  int j0 = blockIdx.x << 6;
  int ob0 = blockIdx.y << 7;
  int b = j0 >> 12;
  int hw0 = j0 & (HW - 1);
  int t = threadIdx.x;
  int wave = t >> 6, lane = t & 63;
  int wj = wave >> 2, wo = wave & 3;
  int lr = lane & 15, lk = lane >> 4;
  int swz = lr & 7;

  // ---- phase 0: corner indices + weights for 64 pixels x 9 n (verified) ----
  for (int e = t; e < 576; e += 512) {
    int n = e >> 6, p = e & 63;
    int hw = hw0 + p;
    int h = hw >> 6, w = hw & 63;
    size_t obi = (((size_t)(b * 18 + n)) << 12) + hw;
    float ox, oy;
    if (isbf) {
      const u16* po = (const u16*)offv;
      ox = b2f(po[obi]);
      oy = b2f(po[obi + (9u << 12)]);
    } else {
      const float* po = (const float*)offv;
      ox = po[obi];
      oy = po[obi + (9u << 12)];
    }
    int ki = n / 3, kj = n % 3;
    float px = (float)(h + ki) + ox;
    float py = (float)(w + kj) + oy;
    float fx = floorf(px), fy = floorf(py);
    float qltx = fminf(fmaxf(fx, 0.f), 65.f);
    float qlty = fminf(fmaxf(fy, 0.f), 65.f);
    float qrbx = fminf(fmaxf(fx + 1.f, 0.f), 65.f);
    float qrby = fminf(fmaxf(fy + 1.f, 0.f), 65.f);
    float pcx = fminf(fmaxf(px, 0.f), 65.f);
    float pcy = fminf(fmaxf(py, 0.f), 65.f);
    float dltx = 1.f + (qltx - pcx);
    float drbx = 1.f - (qrbx - pcx);
    float dlty = 1.f + (qlty - pcy);
    float drby = 1.f - (qrby - pcy);
    float g0 = dltx * dlty;   // (q_lt_x, q_lt_y)
    float g1 = drbx * drby;   // (q_rb_x, q_rb_y)
    float g2 = dltx * drby;   // (q_lt_x, q_rb_y)
    float g3 = drbx * dlty;   // (q_rb_x, q_lt_y)
    int x0 = (int)qltx, y0 = (int)qlty, x1 = (int)qrbx, y1 = (int)qrby;
    int v0 = (x0 >= 1 && x0 <= 64 && y0 >= 1 && y0 <= 64);
    int v1 = (x1 >= 1 && x1 <= 64 && y1 >= 1 && y1 <= 64);
    int v2 = (x0 >= 1 && x0 <= 64 && y1 >= 1 && y1 <= 64);
    int v3 = (x1 >= 1 && x1 <= 64 && y0 >= 1 && y0 <= 64);
    int base = b << 12;
    isx[n][0][p] = v0 ? ((base + ((x0 - 1) << 6) + (y0 - 1)) << 8) : 0;
    isx[n][1][p] = v1 ? ((base + ((x1 - 1) << 6) + (y1 - 1)) << 8) : 0;
    isx[n][2][p] = v2 ? ((base + ((x0 - 1) << 6) + (y1 - 1)) << 8) : 0;
    isx[n][3][p] = v3 ? ((base + ((x1 - 1) << 6) + (y0 - 1)) << 8) : 0;
    gs[n][0][p] = v0 ? g0 : 0.f;
    gs[n][1][p] = v1 ? g1 : 0.f;
    gs[n][2][p] = v2 ? g2 : 0.f;
    gs[n][3][p] = v3 ? g3 : 0.f;
  }

  f32x4 acc[2][2];   // [oi][ji]
  f32x4 zero = {0.f, 0.f, 0.f, 0.f};
#pragma unroll
  for (int i = 0; i < 2; i++)
#pragma unroll
    for (int j = 0; j < 2; j++) acc[i][j] = zero;

  // A staging: wave w stages rows [16w,16w+16) of the block's 128 o-rows via
  // 2 instrs; lane l covers row +(l>>3), source col-group pre-swizzled
  // (l&7)^(l>>3) so LDS slot (r,cg) holds global column (cg ^ (r&7)).
  int rb = lane >> 3;
  int cs = ((lane & 7) ^ rb) << 3;
  const u16* asrc0 = Wr + (size_t)(ob0 + wave * 16 + 0 + rb) * K_TOT + cs;
  const u16* asrc1 = Wr + (size_t)(ob0 + wave * 16 + 8 + rb) * K_TOT + cs;

  // B producer: thread (p = t>>3, cg = t&7) owns one us8 of the 64x64 tile.
  int pp = t >> 3, cg = t & 7;
  int bofs = pp * 64 + ((cg ^ (pp & 7)) << 3);   // swizzled LDS elem offset
  int cb8 = cg << 3;                              // channel offset in 64-chunk

  __syncthreads();   // phase-0 tables ready

  us8 q0, q1, q2, q3;
  float w0, w1, w2, w3;

  // prologue: produce tile 0 + stage A tile 0 into buffer 0
  PLOAD(0);
  A_DMA(0);
  PFIN(0);
  __syncthreads();

  for (int tt = 0; tt < NT - 1; ++tt) {
    int cbuf = tt & 1, nbuf = cbuf ^ 1;
    PLOAD(tt + 1);          // corner loads in flight
    A_DMA(nbuf);            // Wr DMA in flight
    GEMM_COMPUTE(cbuf);     // MFMA on current tile hides the latency
    PFIN(nbuf);             // interp + ds_write next B tile
    __syncthreads();        // drains vmcnt+lgkmcnt; all buffers coherent
  }
  GEMM_COMPUTE((NT - 1) & 1);

  // epilogue: D mapping col = lane&15 (j), row = (lane>>4)*4 + r (o)
  int lq = lane >> 4;
#pragma unroll
  for (int oi = 0; oi < 2; oi++) {
#pragma unroll
    for (int ji = 0; ji < 2; ji++) {
      int j = j0 + wj * 32 + ji * 16 + lr;
      int bb_ = j >> 12, hw = j & (HW - 1);
      int o0 = ob0 + wo * 32 + oi * 16 + lq * 4;
#pragma unroll
      for (int r = 0; r < 4; r++) {
        size_t oidx = (((size_t)(bb_ * C_CH + o0 + r)) << 12) + hw;
        float v = acc[oi][ji][r];
        v = fmaxf(v, 0.f);
        float ft = isbf ? b2f(((const u16*)featv)[oidx]) : ((const float*)featv)[oidx];
        v = fmaxf(v + ft, 0.f);
        if (isbf) ((u16*)outv)[oidx] = f2b(v);
        else      ((float*)outv)[oidx] = v;
      }
    }
  }
}

extern "C" void kernel_launch(void* const* d_in, const int* in_sizes, int n_in,
                              void* d_out, int out_size, void* d_ws, size_t ws_size,
                              hipStream_t stream) {
  const void* feat = d_in[0];
  const void* offs = d_in[1];
  const void* wght = d_in[2];

  // workspace layout (256B-aligned sections); Xt no longer materialized
  const size_t off_flag = 0;
  const size_t off_wr   = 256;                          // bf16 Wr, 1.125 MB
  const size_t off_ftr  = off_wr + (size_t)1179648;     // bf16 channels-last feature, 8 MB
  const size_t need     = off_ftr + (size_t)8388608;
  if (ws_size < need) return;  // insufficient scratch; cannot run

  char* ws = (char*)d_ws;
  int* flag = (int*)(ws + off_flag);
  u16* Wr   = (u16*)(ws + off_wr);
  u16* ftr  = (u16*)(ws + off_ftr);

  k_detect<<<1, 256, 0, stream>>>((const u16*)feat, flag);
  k_prep<<<dim3(128, 8, 5), dim3(32, 8), 0, stream>>>(feat, ftr, wght, Wr, flag);
  k_gemm<<<dim3(J_TOT / 64, 2), 512, 0, stream>>>(Wr, ftr, offs, feat, d_out, flag);
}

// Round 5
// 136.075 us; speedup vs baseline: 1.0657x; 1.0025x over previous
//
#include <hip/hip_runtime.h>

// Problem constants: B=4, C=256, H=W=64, KS=3, N=9
#define HW    4096
#define J_TOT 16384   // B*H*W
#define K_TOT 2304    // 9*256
#define C_CH  256

typedef unsigned short u16;
typedef unsigned int   u32;
typedef __attribute__((ext_vector_type(8))) short short8;   // 8 bf16 (4 VGPRs), MFMA A/B frag
typedef __attribute__((ext_vector_type(4))) float f32x4;    // MFMA C/D frag
typedef __attribute__((ext_vector_type(8))) unsigned short us8;
typedef __attribute__((ext_vector_type(4))) unsigned short us4;

__device__ __forceinline__ float b2f(u16 u) { return __uint_as_float(((u32)u) << 16); }
__device__ __forceinline__ u16 f2b(float x) {             // RNE f32->bf16
  u32 u = __float_as_uint(x);
  u += 0x7FFFu + ((u >> 16) & 1u);
  return (u16)(u >> 16);
}

// async global->LDS, 16B per lane; lds dst must be wave-uniform base (+lane*16 implicit)
__device__ __forceinline__ void gload_lds16(const u16* g, u16* l) {
  __builtin_amdgcn_global_load_lds(
      (__attribute__((address_space(1))) void*)(void*)g,
      (__attribute__((address_space(3))) void*)(void*)l, 16, 0, 0);
}

// ---------------------------------------------------------------------------
// Kernel 0: dtype detection (1 = bf16 inputs, 0 = f32 inputs).
// ---------------------------------------------------------------------------
__global__ void k_detect(const u16* __restrict__ f, int* __restrict__ flag) {
  __shared__ int sh[256];
  int t = threadIdx.x;
  int hits = 0;
  for (int i = t; i < 2048; i += 256) {
    u16 u = f[2 * i];
    int e = (u >> 7) & 0xFF;
    hits += (e >= 100 && e <= 141) ? 1 : 0;
  }
  sh[t] = hits;
  __syncthreads();
  if (t == 0) {
    int s = 0;
    for (int i = 0; i < 256; i++) s += sh[i];
    flag[0] = (s > 1024) ? 1 : 0;
  }
}

// ---------------------------------------------------------------------------
// Kernel 1 (merged prep): z<4 -> feature (b,c,h,w) -> channels-last bf16
// ftr[b][hw][c] (b = blockIdx.z); z==4 -> weight (o,c,3,3) -> Wr[o][k],
// k = n*256+c.
// ---------------------------------------------------------------------------
__global__ void k_prep(const void* __restrict__ featv, u16* __restrict__ ftr,
                       const void* __restrict__ wv, u16* __restrict__ Wr,
                       const int* __restrict__ flag) {
  int isbf = *flag;
  int tx = threadIdx.x;  // 0..31
  int ty = threadIdx.y;  // 0..7
  int z = blockIdx.z;
  if (z < 4) {
    __shared__ u16 tile[32][33];
    int b = z;
    int hw0 = blockIdx.x << 5;
    int c0 = blockIdx.y << 5;
    if (isbf) {
      const u16* f = (const u16*)featv;
#pragma unroll
      for (int i = 0; i < 4; i++) {
        int c = c0 + ty + i * 8;
        tile[ty + i * 8][tx] = f[(((size_t)(b * C_CH + c)) << 12) + hw0 + tx];
      }
    } else {
      const float* f = (const float*)featv;
#pragma unroll
      for (int i = 0; i < 4; i++) {
        int c = c0 + ty + i * 8;
        tile[ty + i * 8][tx] = f2b(f[(((size_t)(b * C_CH + c)) << 12) + hw0 + tx]);
      }
    }
    __syncthreads();
#pragma unroll
    for (int i = 0; i < 4; i++) {
      int hw = hw0 + ty + i * 8;
      ftr[(((size_t)(b * HW + hw)) << 8) + c0 + tx] = tile[tx][ty + i * 8];
    }
  } else {
    // weight repack: grid-stride over 589824 elems
    int bid = blockIdx.x + (blockIdx.y << 7);
    int flat = ty * 32 + tx;
    for (int idx = bid * 256 + flat; idx < C_CH * K_TOT; idx += 1024 * 256) {
      int c = idx & 255;
      int n = (idx >> 8) % 9;
      int o = idx / K_TOT;
      int src = (o * 256 + c) * 9 + n;
      if (isbf) Wr[idx] = ((const u16*)wv)[src];
      else      Wr[idx] = f2b(((const float*)wv)[src]);
    }
  }
}

// ---------------------------------------------------------------------------
// Kernel 2 (FUSED gather+GEMM): out[o][j] = sum_k Wr[o][k]*B[j][k] with
// B[j][n*256+c] = bilinear-gathered feature, produced ON THE FLY in LDS.
//
// Round-5 restructure: dup-1 gather at 4 waves/SIMD. Block = 64j x 256o
// (ALL o => each pixel gathered ONCE, halving round 4's duplicated VALU,
// the top counter at 45% busy), but with 1024 threads = 16 waves (2j x 8o,
// wave tile 32j x 32o, acc[2][2], 8 MFMA/iter/wave). Grid 256 = 1 block/CU
// = 4 waves/SIMD (round 4's TLP) via __launch_bounds__(1024,4) (VGPR<=128).
//
// LDS 98KB: As 2x32KB + Bs 2x8KB + tables 18KB. B producer: thread
// (p = t>>4, q = t&15) owns 4 channels (us4 load, ds_write_b64) of pixel p;
// swizzled slot (p, (cg^(p&7))*8 + half*4), reader group g from slot
// g^(row&7) -- same algebra as rounds 2-4, 0 conflicts measured.
// A staging: wave w stages rows [16w,16w+16) via 2 gload_lds16, source
// column pre-swizzled (l&7)^(l>>3).
// ---------------------------------------------------------------------------
#define NT 36   // K_TOT / 64

#define A_DMA(bufi)                                                          \
  do {                                                                       \
    gload_lds16(asrc0, &As[bufi][wave * 1024]);                              \
    gload_lds16(asrc1, &As[bufi][wave * 1024 + 512]);                        \
    asrc0 += 64; asrc1 += 64;                                                \
  } while (0)

#define PLOAD(tile)                                                          \
  do {                                                                       \
    int np = (tile) >> 2, c0 = ((tile) & 3) << 6;                            \
    w0 = gs[np][0][pp]; w1 = gs[np][1][pp];                                  \
    w2 = gs[np][2][pp]; w3 = gs[np][3][pp];                                  \
    q0 = *(const us4*)(ftr + isx[np][0][pp] + c0 + cb4);                     \
    q1 = *(const us4*)(ftr + isx[np][1][pp] + c0 + cb4);                     \
    q2 = *(const us4*)(ftr + isx[np][2][pp] + c0 + cb4);                     \
    q3 = *(const us4*)(ftr + isx[np][3][pp] + c0 + cb4);                     \
  } while (0)

#define PFIN(bufi)                                                           \
  do {                                                                       \
    us4 ov;                                                                  \
    _Pragma("unroll")                                                        \
    for (int i = 0; i < 4; i++) {                                            \
      float v = w0 * b2f(q0[i]) + w1 * b2f(q1[i]) +                          \
                w2 * b2f(q2[i]) + w3 * b2f(q3[i]);                           \
      ov[i] = f2b(v);                                                        \
    }                                                                        \
    *(us4*)(&Bs[bufi][bofs]) = ov;                                           \
  } while (0)

#define GEMM_COMPUTE(bufi)                                                   \
  do {                                                                       \
    short8 af[2][2], bf[2][2];                                               \
    _Pragma("unroll")                                                        \
    for (int kk = 0; kk < 2; kk++) {                                         \
      int go = (((kk << 2) + lk) ^ swz) << 3;                                \
      _Pragma("unroll")                                                      \
      for (int oi = 0; oi < 2; oi++)                                         \
        af[oi][kk] = *(const short8*)(As[bufi] + (wo * 32 + oi * 16 + lr) * 64 + go); \
      _Pragma("unroll")                                                      \
      for (int ji = 0; ji < 2; ji++)                                         \
        bf[ji][kk] = *(const short8*)(Bs[bufi] + (wj * 32 + ji * 16 + lr) * 64 + go); \
    }                                                                        \
    __builtin_amdgcn_s_setprio(1);                                           \
    _Pragma("unroll")                                                        \
    for (int kk = 0; kk < 2; kk++)                                           \
      _Pragma("unroll")                                                      \
      for (int oi = 0; oi < 2; oi++)                                         \
        _Pragma("unroll")                                                    \
        for (int ji = 0; ji < 2; ji++)                                       \
          acc[oi][ji] = __builtin_amdgcn_mfma_f32_16x16x32_bf16(             \
              af[oi][kk], bf[ji][kk], acc[oi][ji], 0, 0, 0);                 \
    __builtin_amdgcn_s_setprio(0);                                           \
  } while (0)

__global__ __launch_bounds__(1024, 4) void k_gemm(const u16* __restrict__ Wr,
                                                  const u16* __restrict__ ftr,
                                                  const void* __restrict__ offv,
                                                  const void* __restrict__ featv,
                                                  void* __restrict__ outv,
                                                  const int* __restrict__ flag) {
  __shared__ u16 As[2][256 * 64];   // [o_row][k] 32KB x2
  __shared__ u16 Bs[2][64 * 64];    // [j_row][k]  8KB x2
  __shared__ float gs[9][4][64];    // bilinear weights, 9KB
  __shared__ int   isx[9][4][64];   // corner base offsets (elem, row<<8), 9KB
  int isbf = *flag;
  int j0 = blockIdx.x << 6;
  int b = j0 >> 12;
  int hw0 = j0 & (HW - 1);
  int t = threadIdx.x;
  int wave = t >> 6, lane = t & 63;
  int wj = wave >> 3, wo = wave & 7;    // 2j x 8o wave grid
  int lr = lane & 15, lk = lane >> 4;
  int swz = lr & 7;

  // ---- phase 0: corner indices + weights for 64 pixels x 9 n (verified) ----
  if (t < 576) {
    int n = t >> 6, p = t & 63;
    int hw = hw0 + p;
    int h = hw >> 6, w = hw & 63;
    size_t obi = (((size_t)(b * 18 + n)) << 12) + hw;
    float ox, oy;
    if (isbf) {
      const u16* po = (const u16*)offv;
      ox = b2f(po[obi]);
      oy = b2f(po[obi + (9u << 12)]);
    } else {
      const float* po = (const float*)offv;
      ox = po[obi];
      oy = po[obi + (9u << 12)];
    }
    int ki = n / 3, kj = n % 3;
    float px = (float)(h + ki) + ox;
    float py = (float)(w + kj) + oy;
    float fx = floorf(px), fy = floorf(py);
    float qltx = fminf(fmaxf(fx, 0.f), 65.f);
    float qlty = fminf(fmaxf(fy, 0.f), 65.f);
    float qrbx = fminf(fmaxf(fx + 1.f, 0.f), 65.f);
    float qrby = fminf(fmaxf(fy + 1.f, 0.f), 65.f);
    float pcx = fminf(fmaxf(px, 0.f), 65.f);
    float pcy = fminf(fmaxf(py, 0.f), 65.f);
    float dltx = 1.f + (qltx - pcx);
    float drbx = 1.f - (qrbx - pcx);
    float dlty = 1.f + (qlty - pcy);
    float drby = 1.f - (qrby - pcy);
    float g0 = dltx * dlty;   // (q_lt_x, q_lt_y)
    float g1 = drbx * drby;   // (q_rb_x, q_rb_y)
    float g2 = dltx * drby;   // (q_lt_x, q_rb_y)
    float g3 = drbx * dlty;   // (q_rb_x, q_lt_y)
    int x0 = (int)qltx, y0 = (int)qlty, x1 = (int)qrbx, y1 = (int)qrby;
    int v0 = (x0 >= 1 && x0 <= 64 && y0 >= 1 && y0 <= 64);
    int v1 = (x1 >= 1 && x1 <= 64 && y1 >= 1 && y1 <= 64);
    int v2 = (x0 >= 1 && x0 <= 64 && y1 >= 1 && y1 <= 64);
    int v3 = (x1 >= 1 && x1 <= 64 && y0 >= 1 && y0 <= 64);
    int base = b << 12;
    isx[n][0][p] = v0 ? ((base + ((x0 - 1) << 6) + (y0 - 1)) << 8) : 0;
    isx[n][1][p] = v1 ? ((base + ((x1 - 1) << 6) + (y1 - 1)) << 8) : 0;
    isx[n][2][p] = v2 ? ((base + ((x0 - 1) << 6) + (y1 - 1)) << 8) : 0;
    isx[n][3][p] = v3 ? ((base + ((x1 - 1) << 6) + (y0 - 1)) << 8) : 0;
    gs[n][0][p] = v0 ? g0 : 0.f;
    gs[n][1][p] = v1 ? g1 : 0.f;
    gs[n][2][p] = v2 ? g2 : 0.f;
    gs[n][3][p] = v3 ? g3 : 0.f;
  }

  f32x4 acc[2][2];   // [oi][ji]
  f32x4 zero = {0.f, 0.f, 0.f, 0.f};
#pragma unroll
  for (int i = 0; i < 2; i++)
#pragma unroll
    for (int j = 0; j < 2; j++) acc[i][j] = zero;

  // A staging: wave w stages rows [16w,16w+16) of the 256 o-rows via 2
  // instrs; lane l covers row +(l>>3), source col-group pre-swizzled
  // (l&7)^(l>>3) so LDS slot (r,cg) holds global column (cg ^ (r&7)).
  int rb = lane >> 3;
  int cs = ((lane & 7) ^ rb) << 3;
  const u16* asrc0 = Wr + (size_t)(wave * 16 + 0 + rb) * K_TOT + cs;
  const u16* asrc1 = Wr + (size_t)(wave * 16 + 8 + rb) * K_TOT + cs;

  // B producer: thread (p = t>>4, q = t&15) owns 4 channels of pixel p:
  // channel-group cg = q>>1, half = q&1 -> channels cg*8+half*4 .. +4.
  int pp = t >> 4, qq = t & 15;
  int cgp = qq >> 1, half = qq & 1;
  int bofs = pp * 64 + ((cgp ^ (pp & 7)) << 3) + (half << 2);  // swizzled elem offset
  int cb4 = (cgp << 3) + (half << 2);                           // channel offset in 64-chunk

  __syncthreads();   // phase-0 tables ready

  us4 q0, q1, q2, q3;
  float w0, w1, w2, w3;

  // prologue: produce tile 0 + stage A tile 0 into buffer 0
  PLOAD(0);
  A_DMA(0);
  PFIN(0);
  __syncthreads();

  for (int tt = 0; tt < NT - 1; ++tt) {
    int cbuf = tt & 1, nbuf = cbuf ^ 1;
    PLOAD(tt + 1);          // corner loads in flight
    A_DMA(nbuf);            // Wr DMA in flight
    GEMM_COMPUTE(cbuf);     // MFMA on current tile hides the latency
    PFIN(nbuf);             // interp + ds_write next B tile
    __syncthreads();        // drains vmcnt+lgkmcnt; all buffers coherent
  }
  GEMM_COMPUTE((NT - 1) & 1);

  // epilogue: D mapping col = lane&15 (j), row = (lane>>4)*4 + r (o)
  int lq = lane >> 4;
#pragma unroll
  for (int oi = 0; oi < 2; oi++) {
#pragma unroll
    for (int ji = 0; ji < 2; ji++) {
      int j = j0 + wj * 32 + ji * 16 + lr;
      int bb_ = j >> 12, hw = j & (HW - 1);
      int o0 = wo * 32 + oi * 16 + lq * 4;
#pragma unroll
      for (int r = 0; r < 4; r++) {
        size_t oidx = (((size_t)(bb_ * C_CH + o0 + r)) << 12) + hw;
        float v = acc[oi][ji][r];
        v = fmaxf(v, 0.f);
        float ft = isbf ? b2f(((const u16*)featv)[oidx]) : ((const float*)featv)[oidx];
        v = fmaxf(v + ft, 0.f);
        if (isbf) ((u16*)outv)[oidx] = f2b(v);
        else      ((float*)outv)[oidx] = v;
      }
    }
  }
}

extern "C" void kernel_launch(void* const* d_in, const int* in_sizes, int n_in,
                              void* d_out, int out_size, void* d_ws, size_t ws_size,
                              hipStream_t stream) {
  const void* feat = d_in[0];
  const void* offs = d_in[1];
  const void* wght = d_in[2];

  // workspace layout (256B-aligned sections); Xt no longer materialized
  const size_t off_flag = 0;
  const size_t off_wr   = 256;                          // bf16 Wr, 1.125 MB
  const size_t off_ftr  = off_wr + (size_t)1179648;     // bf16 channels-last feature, 8 MB
  const size_t need     = off_ftr + (size_t)8388608;
  if (ws_size < need) return;  // insufficient scratch; cannot run

  char* ws = (char*)d_ws;
  int* flag = (int*)(ws + off_flag);
  u16* Wr   = (u16*)(ws + off_wr);
  u16* ftr  = (u16*)(ws + off_ftr);

  k_detect<<<1, 256, 0, stream>>>((const u16*)feat, flag);
  k_prep<<<dim3(128, 8, 5), dim3(32, 8), 0, stream>>>(feat, ftr, wght, Wr, flag);
  k_gemm<<<J_TOT / 64, 1024, 0, stream>>>(Wr, ftr, offs, feat, d_out, flag);
}

// Round 6
// 128.020 us; speedup vs baseline: 1.1328x; 1.0629x over previous
//
#include <hip/hip_runtime.h>

// Problem constants: B=4, C=256, H=W=64, KS=3, N=9
#define HW    4096
#define J_TOT 16384   // B*H*W
#define K_TOT 2304    // 9*256
#define C_CH  256

typedef unsigned short u16;
typedef unsigned int   u32;
typedef __attribute__((ext_vector_type(8))) short short8;   // 8 bf16 (4 VGPRs), MFMA A/B frag
typedef __attribute__((ext_vector_type(4))) float f32x4;    // MFMA C/D frag
typedef __attribute__((ext_vector_type(4))) unsigned short us4;

__device__ __forceinline__ float b2f(u16 u) { return __uint_as_float(((u32)u) << 16); }
__device__ __forceinline__ u16 f2b(float x) {             // RNE f32->bf16
  u32 u = __float_as_uint(x);
  u += 0x7FFFu + ((u >> 16) & 1u);
  return (u16)(u >> 16);
}

// async global->LDS, 16B per lane; lds dst must be wave-uniform base (+lane*16 implicit)
__device__ __forceinline__ void gload_lds16(const u16* g, u16* l) {
  __builtin_amdgcn_global_load_lds(
      (__attribute__((address_space(1))) void*)(void*)g,
      (__attribute__((address_space(3))) void*)(void*)l, 16, 0, 0);
}

// ---------------------------------------------------------------------------
// Kernel 0: dtype detection (1 = bf16 inputs, 0 = f32 inputs).
// ---------------------------------------------------------------------------
__global__ void k_detect(const u16* __restrict__ f, int* __restrict__ flag) {
  __shared__ int sh[256];
  int t = threadIdx.x;
  int hits = 0;
  for (int i = t; i < 2048; i += 256) {
    u16 u = f[2 * i];
    int e = (u >> 7) & 0xFF;
    hits += (e >= 100 && e <= 141) ? 1 : 0;
  }
  sh[t] = hits;
  __syncthreads();
  if (t == 0) {
    int s = 0;
    for (int i = 0; i < 256; i++) s += sh[i];
    flag[0] = (s > 1024) ? 1 : 0;
  }
}

// ---------------------------------------------------------------------------
// Kernel 1 (merged prep): z<4 -> feature (b,c,h,w) -> channels-last bf16
// ftr[b][hw][c] (b = blockIdx.z); z==4 -> weight (o,c,3,3) -> Wr[o][k],
// k = n*256+c.
// ---------------------------------------------------------------------------
__global__ void k_prep(const void* __restrict__ featv, u16* __restrict__ ftr,
                       const void* __restrict__ wv, u16* __restrict__ Wr,
                       const int* __restrict__ flag) {
  int isbf = *flag;
  int tx = threadIdx.x;  // 0..31
  int ty = threadIdx.y;  // 0..7
  int z = blockIdx.z;
  if (z < 4) {
    __shared__ u16 tile[32][33];
    int b = z;
    int hw0 = blockIdx.x << 5;
    int c0 = blockIdx.y << 5;
    if (isbf) {
      const u16* f = (const u16*)featv;
#pragma unroll
      for (int i = 0; i < 4; i++) {
        int c = c0 + ty + i * 8;
        tile[ty + i * 8][tx] = f[(((size_t)(b * C_CH + c)) << 12) + hw0 + tx];
      }
    } else {
      const float* f = (const float*)featv;
#pragma unroll
      for (int i = 0; i < 4; i++) {
        int c = c0 + ty + i * 8;
        tile[ty + i * 8][tx] = f2b(f[(((size_t)(b * C_CH + c)) << 12) + hw0 + tx]);
      }
    }
    __syncthreads();
#pragma unroll
    for (int i = 0; i < 4; i++) {
      int hw = hw0 + ty + i * 8;
      ftr[(((size_t)(b * HW + hw)) << 8) + c0 + tx] = tile[tx][ty + i * 8];
    }
  } else {
    // weight repack: grid-stride over 589824 elems
    int bid = blockIdx.x + (blockIdx.y << 7);
    int flat = ty * 32 + tx;
    for (int idx = bid * 256 + flat; idx < C_CH * K_TOT; idx += 1024 * 256) {
      int c = idx & 255;
      int n = (idx >> 8) % 9;
      int o = idx / K_TOT;
      int src = (o * 256 + c) * 9 + n;
      if (isbf) Wr[idx] = ((const u16*)wv)[src];
      else      Wr[idx] = f2b(((const float*)wv)[src]);
    }
  }
}

// ---------------------------------------------------------------------------
// Kernel 2 (FUSED gather+GEMM): out[o][j] = sum_k Wr[o][k]*B[j][k] with
// B[j][n*256+c] = bilinear-gathered feature, produced ON THE FLY in LDS.
//
// Round-6: attack the measured LDS-pipe budget (~66% subscribed at r5):
//  (a) np-cадenced table cache: gs/isx read from LDS only when np=tile>>2
//      changes (every 4 tiles), kept in regs -- removes 128 LDS
//      wave-instrs/iter (~550 cyc of ~4200).
//  (b) TRIPLE-buffered As/Bs (138KB LDS total): corner q-regs for tile
//      tt+2 are loaded at iter tt and consumed by PFIN at iter tt+1 --
//      full-iteration latency cover (was: GEMM_COMPUTE only).
//  (c) counted barrier: s_waitcnt vmcnt(6) lgkmcnt(0) + s_barrier. Per
//      wave per iter exactly 6 VMEM ops issue (4 corner q + 2 A-DMA);
//      vmcnt(6) retires last iter's A-DMA (needed by next GEMM_COMPUTE)
//      while this iter's stay in flight. Same construct as rounds 1-2.
//
// Block = 64j x 256o, 1024 threads = 16 waves (2j x 8o), wave tile 32jx32o
// (acc[2][2], 8 MFMA/iter). Grid 256 = 1 block/CU = 4 waves/SIMD.
// Swizzle unchanged (slot cg^(p&7), reader g^(row&7); 0 conflicts measured).
// ---------------------------------------------------------------------------
#define NT 36   // K_TOT / 64

#define A_DMA(Ab)                                                            \
  do {                                                                       \
    gload_lds16(asrc0, (Ab) + wave * 1024);                                  \
    gload_lds16(asrc1, (Ab) + wave * 1024 + 512);                            \
    asrc0 += 64; asrc1 += 64;                                                \
  } while (0)

// load corner q-regs + snapshot weights for `tile` into slot P (a or b)
#define PLOAD_S(tile, P)                                                     \
  do {                                                                       \
    if (((tile) & 3) == 0) {                                                 \
      int np_ = (tile) >> 2;                                                 \
      tw0 = gs[np_][0][pp]; tw1 = gs[np_][1][pp];                            \
      tw2 = gs[np_][2][pp]; tw3 = gs[np_][3][pp];                            \
      ti0 = isx[np_][0][pp]; ti1 = isx[np_][1][pp];                          \
      ti2 = isx[np_][2][pp]; ti3 = isx[np_][3][pp];                          \
    }                                                                        \
    int c0_ = (((tile) & 3) << 6) + cb4;                                     \
    P##w0 = tw0; P##w1 = tw1; P##w2 = tw2; P##w3 = tw3;                      \
    P##q0 = *(const us4*)(ftr + ti0 + c0_);                                  \
    P##q1 = *(const us4*)(ftr + ti1 + c0_);                                  \
    P##q2 = *(const us4*)(ftr + ti2 + c0_);                                  \
    P##q3 = *(const us4*)(ftr + ti3 + c0_);                                  \
  } while (0)

#define PFIN_S(P, Bb)                                                        \
  do {                                                                       \
    us4 ov;                                                                  \
    _Pragma("unroll")                                                        \
    for (int i = 0; i < 4; i++) {                                            \
      float v = P##w0 * b2f(P##q0[i]) + P##w1 * b2f(P##q1[i]) +              \
                P##w2 * b2f(P##q2[i]) + P##w3 * b2f(P##q3[i]);               \
      ov[i] = f2b(v);                                                        \
    }                                                                        \
    *(us4*)((Bb) + bofs) = ov;                                               \
  } while (0)

#define GEMM_COMPUTE(Ab, Bb)                                                 \
  do {                                                                       \
    short8 af[2][2], bf[2][2];                                               \
    _Pragma("unroll")                                                        \
    for (int kk = 0; kk < 2; kk++) {                                         \
      int go = (((kk << 2) + lk) ^ swz) << 3;                                \
      _Pragma("unroll")                                                      \
      for (int oi = 0; oi < 2; oi++)                                         \
        af[oi][kk] = *(const short8*)((Ab) + (wo * 32 + oi * 16 + lr) * 64 + go); \
      _Pragma("unroll")                                                      \
      for (int ji = 0; ji < 2; ji++)                                         \
        bf[ji][kk] = *(const short8*)((Bb) + (wj * 32 + ji * 16 + lr) * 64 + go); \
    }                                                                        \
    __builtin_amdgcn_s_setprio(1);                                           \
    _Pragma("unroll")                                                        \
    for (int kk = 0; kk < 2; kk++)                                           \
      _Pragma("unroll")                                                      \
      for (int oi = 0; oi < 2; oi++)                                         \
        _Pragma("unroll")                                                    \
        for (int ji = 0; ji < 2; ji++)                                       \
          acc[oi][ji] = __builtin_amdgcn_mfma_f32_16x16x32_bf16(             \
              af[oi][kk], bf[ji][kk], acc[oi][ji], 0, 0, 0);                 \
    __builtin_amdgcn_s_setprio(0);                                           \
  } while (0)

#define CBAR()                                                               \
  do {                                                                       \
    asm volatile("s_waitcnt vmcnt(6) lgkmcnt(0)" ::: "memory");              \
    __builtin_amdgcn_s_barrier();                                            \
  } while (0)

#define ROTATE()                                                             \
  do {                                                                       \
    u16* tp_ = Ac; Ac = An; An = Af; Af = tp_;                               \
    tp_ = Bc; Bc = Bn; Bn = Bf; Bf = tp_;                                    \
  } while (0)

__global__ __launch_bounds__(1024, 4) void k_gemm(const u16* __restrict__ Wr,
                                                  const u16* __restrict__ ftr,
                                                  const void* __restrict__ offv,
                                                  const void* __restrict__ featv,
                                                  void* __restrict__ outv,
                                                  const int* __restrict__ flag) {
  __shared__ u16 As[3][256 * 64];   // [o_row][k] 32KB x3
  __shared__ u16 Bs[3][64 * 64];    // [j_row][k]  8KB x3
  __shared__ float gs[9][4][64];    // bilinear weights, 9KB
  __shared__ int   isx[9][4][64];   // corner base offsets (elem, row<<8), 9KB
  int isbf = *flag;
  asm volatile("" :: "s"(isbf));
  int j0 = blockIdx.x << 6;
  int b = j0 >> 12;
  int hw0 = j0 & (HW - 1);
  int t = threadIdx.x;
  int wave = t >> 6, lane = t & 63;
  int wj = wave >> 3, wo = wave & 7;    // 2j x 8o wave grid
  int lr = lane & 15, lk = lane >> 4;
  int swz = lr & 7;

  // ---- phase 0: corner indices + weights for 64 pixels x 9 n (verified) ----
  if (t < 576) {
    int n = t >> 6, p = t & 63;
    int hw = hw0 + p;
    int h = hw >> 6, w = hw & 63;
    size_t obi = (((size_t)(b * 18 + n)) << 12) + hw;
    float ox, oy;
    if (isbf) {
      const u16* po = (const u16*)offv;
      ox = b2f(po[obi]);
      oy = b2f(po[obi + (9u << 12)]);
    } else {
      const float* po = (const float*)offv;
      ox = po[obi];
      oy = po[obi + (9u << 12)];
    }
    int ki = n / 3, kj = n % 3;
    float px = (float)(h + ki) + ox;
    float py = (float)(w + kj) + oy;
    float fx = floorf(px), fy = floorf(py);
    float qltx = fminf(fmaxf(fx, 0.f), 65.f);
    float qlty = fminf(fmaxf(fy, 0.f), 65.f);
    float qrbx = fminf(fmaxf(fx + 1.f, 0.f), 65.f);
    float qrby = fminf(fmaxf(fy + 1.f, 0.f), 65.f);
    float pcx = fminf(fmaxf(px, 0.f), 65.f);
    float pcy = fminf(fmaxf(py, 0.f), 65.f);
    float dltx = 1.f + (qltx - pcx);
    float drbx = 1.f - (qrbx - pcx);
    float dlty = 1.f + (qlty - pcy);
    float drby = 1.f - (qrby - pcy);
    float g0 = dltx * dlty;   // (q_lt_x, q_lt_y)
    float g1 = drbx * drby;   // (q_rb_x, q_rb_y)
    float g2 = dltx * drby;   // (q_lt_x, q_rb_y)
    float g3 = drbx * dlty;   // (q_rb_x, q_lt_y)
    int x0 = (int)qltx, y0 = (int)qlty, x1 = (int)qrbx, y1 = (int)qrby;
    int v0 = (x0 >= 1 && x0 <= 64 && y0 >= 1 && y0 <= 64);
    int v1 = (x1 >= 1 && x1 <= 64 && y1 >= 1 && y1 <= 64);
    int v2 = (x0 >= 1 && x0 <= 64 && y1 >= 1 && y1 <= 64);
    int v3 = (x1 >= 1 && x1 <= 64 && y0 >= 1 && y0 <= 64);
    int base = b << 12;
    isx[n][0][p] = v0 ? ((base + ((x0 - 1) << 6) + (y0 - 1)) << 8) : 0;
    isx[n][1][p] = v1 ? ((base + ((x1 - 1) << 6) + (y1 - 1)) << 8) : 0;
    isx[n][2][p] = v2 ? ((base + ((x0 - 1) << 6) + (y1 - 1)) << 8) : 0;
    isx[n][3][p] = v3 ? ((base + ((x1 - 1) << 6) + (y0 - 1)) << 8) : 0;
    gs[n][0][p] = v0 ? g0 : 0.f;
    gs[n][1][p] = v1 ? g1 : 0.f;
    gs[n][2][p] = v2 ? g2 : 0.f;
    gs[n][3][p] = v3 ? g3 : 0.f;
  }

  f32x4 acc[2][2];   // [oi][ji]
  f32x4 zero = {0.f, 0.f, 0.f, 0.f};
#pragma unroll
  for (int i = 0; i < 2; i++)
#pragma unroll
    for (int j = 0; j < 2; j++) acc[i][j] = zero;

  // A staging: wave w stages rows [16w,16w+16) of the 256 o-rows via 2
  // instrs; lane l covers row +(l>>3), source col-group pre-swizzled
  // (l&7)^(l>>3) so LDS slot (r,cg) holds global column (cg ^ (r&7)).
  int rb = lane >> 3;
  int cs = ((lane & 7) ^ rb) << 3;
  const u16* asrc0 = Wr + (size_t)(wave * 16 + 0 + rb) * K_TOT + cs;
  const u16* asrc1 = Wr + (size_t)(wave * 16 + 8 + rb) * K_TOT + cs;

  // B producer: thread (p = t>>4, q = t&15) owns 4 channels of pixel p:
  // channel-group cg = q>>1, half = q&1 -> channels cg*8+half*4 .. +4.
  int pp = t >> 4, qq = t & 15;
  int cgp = qq >> 1, half = qq & 1;
  int bofs = pp * 64 + ((cgp ^ (pp & 7)) << 3) + (half << 2);  // swizzled elem offset
  int cb4 = (cgp << 3) + (half << 2);                           // channel offset in 64-chunk

  u16 *Ac = &As[0][0], *An = &As[1][0], *Af = &As[2][0];
  u16 *Bc = &Bs[0][0], *Bn = &Bs[1][0], *Bf = &Bs[2][0];

  __syncthreads();   // phase-0 tables ready

  us4 aq0, aq1, aq2, aq3, bq0, bq1, bq2, bq3;
  float aw0, aw1, aw2, aw3, bw0, bw1, bw2, bw3;
  float tw0, tw1, tw2, tw3;
  int ti0, ti1, ti2, ti3;

  // prologue: tile0 -> cur (B produced immediately), tile1 -> nxt (A only;
  // B for tile1 produced in the first loop iteration)
  PLOAD_S(0, a); A_DMA(Ac);
  PFIN_S(a, Bc);
  PLOAD_S(1, b); A_DMA(An);
  CBAR();   // retires tile0's A-DMA; tile1's 6 ops stay in flight

  // main loop: 34 sub-iters (tiles 0..33 computed), 2-unrolled for slot parity
#pragma unroll 1
  for (int it = 0; it < 17; ++it) {
    // even sub-iter: compute tile 2*it, produce B tile 2*it+1, prefetch 2*it+2
    PLOAD_S(2 * it + 2, a);
    A_DMA(Af);
    GEMM_COMPUTE(Ac, Bc);
    PFIN_S(b, Bn);
    CBAR();
    ROTATE();
    // odd sub-iter
    PLOAD_S(2 * it + 3, b);
    A_DMA(Af);
    GEMM_COMPUTE(Ac, Bc);
    PFIN_S(a, Bn);
    CBAR();
    ROTATE();
  }
  // epilogue: tiles 34, 35
  GEMM_COMPUTE(Ac, Bc);          // tile 34
  PFIN_S(b, Bn);                 // tile 35 B (slot b loaded at sub-iter tt=33)
  asm volatile("s_waitcnt vmcnt(0) lgkmcnt(0)" ::: "memory");
  __builtin_amdgcn_s_barrier();
  GEMM_COMPUTE(An, Bn);          // tile 35

  // epilogue: D mapping col = lane&15 (j), row = (lane>>4)*4 + r (o)
  int lq = lane >> 4;
#pragma unroll
  for (int oi = 0; oi < 2; oi++) {
#pragma unroll
    for (int ji = 0; ji < 2; ji++) {
      int j = j0 + wj * 32 + ji * 16 + lr;
      int bb_ = j >> 12, hw = j & (HW - 1);
      int o0 = wo * 32 + oi * 16 + lq * 4;
#pragma unroll
      for (int r = 0; r < 4; r++) {
        size_t oidx = (((size_t)(bb_ * C_CH + o0 + r)) << 12) + hw;
        float v = acc[oi][ji][r];
        v = fmaxf(v, 0.f);
        float ft = isbf ? b2f(((const u16*)featv)[oidx]) : ((const float*)featv)[oidx];
        v = fmaxf(v + ft, 0.f);
        if (isbf) ((u16*)outv)[oidx] = f2b(v);
        else      ((float*)outv)[oidx] = v;
      }
    }
  }
}

extern "C" void kernel_launch(void* const* d_in, const int* in_sizes, int n_in,
                              void* d_out, int out_size, void* d_ws, size_t ws_size,
                              hipStream_t stream) {
  const void* feat = d_in[0];
  const void* offs = d_in[1];
  const void* wght = d_in[2];

  // workspace layout (256B-aligned sections); Xt no longer materialized
  const size_t off_flag = 0;
  const size_t off_wr   = 256;                          // bf16 Wr, 1.125 MB
  const size_t off_ftr  = off_wr + (size_t)1179648;     // bf16 channels-last feature, 8 MB
  const size_t need     = off_ftr + (size_t)8388608;
  if (ws_size < need) return;  // insufficient scratch; cannot run

  char* ws = (char*)d_ws;
  int* flag = (int*)(ws + off_flag);
  u16* Wr   = (u16*)(ws + off_wr);
  u16* ftr  = (u16*)(ws + off_ftr);

  k_detect<<<1, 256, 0, stream>>>((const u16*)feat, flag);
  k_prep<<<dim3(128, 8, 5), dim3(32, 8), 0, stream>>>(feat, ftr, wght, Wr, flag);
  k_gemm<<<J_TOT / 64, 1024, 0, stream>>>(Wr, ftr, offs, feat, d_out, flag);
}